// Round 1
// 367.282 us; speedup vs baseline: 1.0668x; 1.0668x over previous
//
#include <hip/hip_runtime.h>

// Problem constants (from reference): E=8, N=8192, D=1024, LOAD=16384
#define D_CONST    1024
#define CAP        64   // bucket capacity; mean occupancy 4 (Poisson) -> overflow ~impossible,
                        // but gather has a correct full-scan fallback if it happens.

typedef float v4f __attribute__((ext_vector_type(4)));

// Kernel 1: one thread per input row; count tags and record row index in bucket.
__global__ void gr_build_index(const int* __restrict__ tags,
                               int* __restrict__ counts,
                               int* __restrict__ idx,
                               int total) {
    int i = blockIdx.x * blockDim.x + threadIdx.x;
    if (i >= total) return;
    int t = tags[i];
    int pos = atomicAdd(&counts[t], 1);   // device-scope by default
    if (pos < CAP) idx[t * CAP + pos] = i;
}

// Kernel 2: one block per TWO output rows. 512 threads; each 256-thread half
// owns one row (256 x float4 = 1024 floats = D). Row indices are prefetched
// 4-at-a-time (uniform int4 load); all 4 row reads are issued independently.
// Tail handling is branchless: invalid slots are clamped to the group's first
// index (always valid since j < cnt) and zero-weighted — no dependent scalar
// tail, no deref of poisoned idx slots.
__global__ void __launch_bounds__(512)
gr_gather_sum(const float* __restrict__ data,
              const int* __restrict__ counts,
              const int* __restrict__ idx,
              const int* __restrict__ tags,
              float* __restrict__ out,
              int total) {
    const int r   = (blockIdx.x << 1) + (threadIdx.x >> 8);   // output row
    const int col = (threadIdx.x & 255) << 2;                 // float offset in row
    const int cnt = counts[r];

    v4f acc = {0.f, 0.f, 0.f, 0.f};

    if (cnt <= CAP) {
        const int* __restrict__ rowlist = idx + r * CAP;
        for (int j = 0; j < cnt; j += 4) {
            const int4 rw = *reinterpret_cast<const int4*>(rowlist + j);  // uniform 16B
            // rw.x is always valid (j < cnt). Clamp the rest so addresses are
            // always dereferenceable; duplicates hit L1, weights zero them out.
            const bool vy = (j + 1) < cnt;
            const bool vz = (j + 2) < cnt;
            const bool vw = (j + 3) < cnt;
            const int ry = vy ? rw.y : rw.x;
            const int rz = vz ? rw.z : rw.x;
            const int rv = vw ? rw.w : rw.x;

            const v4f v0 = __builtin_nontemporal_load(
                reinterpret_cast<const v4f*>(data + (size_t)rw.x * D_CONST + col));
            const v4f v1 = __builtin_nontemporal_load(
                reinterpret_cast<const v4f*>(data + (size_t)ry * D_CONST + col));
            const v4f v2 = __builtin_nontemporal_load(
                reinterpret_cast<const v4f*>(data + (size_t)rz * D_CONST + col));
            const v4f v3 = __builtin_nontemporal_load(
                reinterpret_cast<const v4f*>(data + (size_t)rv * D_CONST + col));

            const float my = vy ? 1.f : 0.f;
            const float mz = vz ? 1.f : 0.f;
            const float mw = vw ? 1.f : 0.f;
            acc += v0 + v1 * my + v2 * mz + v3 * mw;
        }
    } else {
        // Overflow fallback (statistically never taken): scan all tags, sum matches.
        for (int i = 0; i < total; ++i) {
            if (tags[i] == r) {
                const v4f v = *reinterpret_cast<const v4f*>(data + (size_t)i * D_CONST + col);
                acc += v;
            }
        }
    }

    // Single-touch streaming store (cnt==0 -> zeros).
    __builtin_nontemporal_store(acc,
        reinterpret_cast<v4f*>(out + (size_t)r * D_CONST + col));
}

// Fallback: direct atomic scatter if workspace is too small (needs zeroed out).
__global__ void __launch_bounds__(256)
gr_atomic_scatter(const float* __restrict__ data,
                  const int* __restrict__ tags,
                  float* __restrict__ out,
                  int total) {
    const int row = blockIdx.x;
    if (row >= total) return;
    const int t = tags[row];
    const int col = threadIdx.x * 4;
    const float4 v = *reinterpret_cast<const float4*>(data + (size_t)row * D_CONST + col);
    float* dst = out + (size_t)t * D_CONST + col;
    atomicAdd(&dst[0], v.x);
    atomicAdd(&dst[1], v.y);
    atomicAdd(&dst[2], v.z);
    atomicAdd(&dst[3], v.w);
}

extern "C" void kernel_launch(void* const* d_in, const int* in_sizes, int n_in,
                              void* d_out, int out_size, void* d_ws, size_t ws_size,
                              hipStream_t stream) {
    const float* data = (const float*)d_in[0];   // (E,N,D) fp32
    const int*   tags = (const int*)d_in[1];     // (E,N) int32
    const int total = in_sizes[1];               // E*N = 65536
    const int load  = out_size / D_CONST;        // 16384
    float* out = (float*)d_out;

    // Workspace layout: [counts: load ints][idx: load*CAP ints]
    const size_t counts_bytes = (size_t)load * sizeof(int);
    const size_t idx_bytes    = (size_t)load * CAP * sizeof(int);
    const size_t needed       = counts_bytes + idx_bytes;

    if (ws_size >= needed) {
        int* counts = (int*)d_ws;
        int* idx    = (int*)((char*)d_ws + counts_bytes);

        hipMemsetAsync(counts, 0, counts_bytes, stream);
        gr_build_index<<<(total + 255) / 256, 256, 0, stream>>>(tags, counts, idx, total);
        gr_gather_sum<<<load / 2, 512, 0, stream>>>(data, counts, idx, tags, out, total);
    } else {
        hipMemsetAsync(out, 0, (size_t)out_size * sizeof(float), stream);
        gr_atomic_scatter<<<total, 256, 0, stream>>>(data, tags, out, total);
    }
}